// Round 3
// baseline (608.888 us; speedup 1.0000x reference)
//
#include <hip/hip_runtime.h>
#include <hip/hip_bf16.h>
#include <math.h>

#define T_TOK 4096
#define D_DIM 1024
#define E_EXP 8
#define F_DIM 4096
#define BM 128
#define BN 128
#define BK 32
#define LDK 40          // fallback path only
#define MAX_TILES 40    // sum_e ceil(cnt_e/128) <= 4096/128 + 7 = 39
#define KSPLIT 4

typedef __attribute__((ext_vector_type(8))) short short8;
typedef __attribute__((ext_vector_type(4))) short short4v;
typedef __attribute__((ext_vector_type(4))) float float4v;

__device__ __forceinline__ short f2b(float f) {
    union { float f; unsigned u; } v; v.f = f;
    unsigned r = v.u + 0x7fffu + ((v.u >> 16) & 1u);   // RNE to bf16
    return (short)(r >> 16);
}

// async global->LDS, 16B per lane; LDS dest must be wave-uniform base (+lane*16 implicit)
typedef const __attribute__((address_space(1))) unsigned gu32;
typedef __attribute__((address_space(3))) unsigned lu32;
__device__ __forceinline__ void gload16(const void* g, void* l) {
    __builtin_amdgcn_global_load_lds((gu32*)g, (lu32*)l, 16, 0, 0);
}

// ---------------- router: fp32 logits + argmax (exact routing) ----------------
__global__ void router_kernel(const float* __restrict__ x, const float* __restrict__ gw,
                              int* __restrict__ eid, int* __restrict__ rnk,
                              int* __restrict__ counts) {
    int lane = threadIdx.x & 63;
    int wave = threadIdx.x >> 6;
    int t = blockIdx.x * 4 + wave;
    const float* xr = x + (size_t)t * D_DIM;
    float p[E_EXP];
#pragma unroll
    for (int e = 0; e < E_EXP; ++e) p[e] = 0.f;
#pragma unroll
    for (int i = 0; i < D_DIM / 64; ++i) {
        float v = xr[lane + 64 * i];
#pragma unroll
        for (int e = 0; e < E_EXP; ++e)
            p[e] = fmaf(v, gw[e * D_DIM + lane + 64 * i], p[e]);
    }
#pragma unroll
    for (int off = 32; off > 0; off >>= 1) {
#pragma unroll
        for (int e = 0; e < E_EXP; ++e) p[e] += __shfl_down(p[e], off, 64);
    }
    if (lane == 0) {
        int best = 0; float bv = p[0];
#pragma unroll
        for (int e = 1; e < E_EXP; ++e) if (p[e] > bv) { bv = p[e]; best = e; }
        eid[t] = best;
        rnk[t] = atomicAdd(&counts[best], 1);
    }
}

// ---------------- prefix + tile map ----------------
__global__ void prefix_kernel(const int* __restrict__ counts, int* __restrict__ offsets,
                              int* __restrict__ tmap) {
    int off = 0;
    offsets[0] = 0;
    int nt = 0;
    for (int e = 0; e < E_EXP; ++e) {
        int c = counts[e];
        for (int m0 = 0; m0 < c; m0 += BM) {
            tmap[nt * 3 + 0] = e;
            tmap[nt * 3 + 1] = off + m0;
            tmap[nt * 3 + 2] = (c - m0 < BM) ? (c - m0) : BM;
            ++nt;
        }
        off += c;
        offsets[e + 1] = off;
    }
    for (; nt < MAX_TILES; ++nt) tmap[nt * 3 + 2] = 0;
}

__global__ void scatter_kernel(const int* __restrict__ eid, const int* __restrict__ rnk,
                               const int* __restrict__ offsets, int* __restrict__ sorted) {
    int t = blockIdx.x * 256 + threadIdx.x;
    sorted[offsets[eid[t]] + rnk[t]] = t;
}

// ---------------- bf16 convert (x) ----------------
__global__ __launch_bounds__(256) void xcvt_kernel(const float* __restrict__ src,
                                                   short* __restrict__ dst) {
    size_t i = ((size_t)blockIdx.x * 256 + threadIdx.x) * 4;
    float4v v = *(const float4v*)(src + i);
    short4v w;
#pragma unroll
    for (int q = 0; q < 4; ++q) w[q] = f2b(v[q]);
    *(short4v*)(dst + i) = w;
}

// ---------------- fp32 (E,R,C) -> bf16 (E,C,R) transpose+convert, 16B stores ----------------
__global__ __launch_bounds__(256) void transpose_cvt(const float* __restrict__ src,
                                                     short* __restrict__ dst,
                                                     int R, int C) {
    __shared__ float t[64][65];
    size_t eoff = (size_t)blockIdx.z * R * C;
    const float* s = src + eoff;
    short* d = dst + eoff;
    int c0 = blockIdx.x * 64, r0 = blockIdx.y * 64;
    int tr = threadIdx.x >> 4;            // 0..15
    int tc = (threadIdx.x & 15) * 4;      // 0..60
#pragma unroll
    for (int p = 0; p < 4; ++p) {
        int r = tr + p * 16;
        float4v v = *(const float4v*)(s + (size_t)(r0 + r) * C + (c0 + tc));
        t[r][tc + 0] = v[0]; t[r][tc + 1] = v[1]; t[r][tc + 2] = v[2]; t[r][tc + 3] = v[3];
    }
    __syncthreads();
    // each thread emits two 16B stores: 16 consecutive k for one n
    int nl = threadIdx.x >> 2;            // 0..63
    int kl = (threadIdx.x & 3) * 16;      // 0,16,32,48
    short8 w0, w1;
#pragma unroll
    for (int q = 0; q < 8; ++q) { w0[q] = f2b(t[kl + q][nl]); w1[q] = f2b(t[kl + 8 + q][nl]); }
    short* dp = d + (size_t)(c0 + nl) * R + (r0 + kl);
    *(short8*)(dp) = w0;
    *(short8*)(dp + 8) = w1;
}

// ==================== PRIMARY PATH: dbuf bf16 GEMMs ====================
// LDS layout per buffer: chunk-linear [c][m], c = k-octet (0..3), m = row (0..127).
// Slot s (s=0..7) = one wave-wide global_load_lds.  One barrier per K-iter:
// prefetch next tile into buf^1 right after the barrier, compute on buf.

__global__ __launch_bounds__(256) void gemm1_kernel(const short* __restrict__ xb,
                                                    const short* __restrict__ w1t,
                                                    const int* __restrict__ sorted,
                                                    const int* __restrict__ tmap,
                                                    short* __restrict__ hb) {
    __shared__ __align__(16) short As[2][4096];
    __shared__ __align__(16) short Bs[2][4096];
    __shared__ int srow[BM];
    int mt = blockIdx.y;
    int m_count = tmap[mt * 3 + 2];
    if (m_count == 0) return;
    int e = tmap[mt * 3 + 0];
    int row0 = tmap[mt * 3 + 1];
    int n0 = blockIdx.x * BN;
    int tid = threadIdx.x;
    if (tid < BM) srow[tid] = sorted[row0 + (tid < m_count ? tid : m_count - 1)];
    __syncthreads();

    int lane = tid & 63, wave = tid >> 6;
    int wm = (wave & 1) * 64, wn = (wave >> 1) * 64;
    int s0 = 2 * wave, s1 = s0 + 1;
    int c0s = s0 >> 1, m0s = (s0 & 1) * 64 + lane;
    int c1s = s1 >> 1, m1s = (s1 & 1) * 64 + lane;
    const short* aptr0 = xb + (size_t)srow[m0s] * D_DIM + c0s * 8;
    const short* aptr1 = xb + (size_t)srow[m1s] * D_DIM + c1s * 8;
    const short* wbase = w1t + (size_t)e * F_DIM * D_DIM;
    const short* bptr0 = wbase + (size_t)(n0 + m0s) * D_DIM + c0s * 8;
    const short* bptr1 = wbase + (size_t)(n0 + m1s) * D_DIM + c1s * 8;
    short* al0[2] = { &As[0][s0 * 512], &As[1][s0 * 512] };
    short* al1[2] = { &As[0][s1 * 512], &As[1][s1 * 512] };
    short* bl0[2] = { &Bs[0][s0 * 512], &Bs[1][s0 * 512] };
    short* bl1[2] = { &Bs[0][s1 * 512], &Bs[1][s1 * 512] };

    float4v acc[4][4];
#pragma unroll
    for (int i = 0; i < 4; ++i)
#pragma unroll
        for (int j = 0; j < 4; ++j) acc[i][j] = (float4v)(0.f);

    int cr = (lane >> 4) * 128;
    int lm = lane & 15;
    // prologue: stage k0=0 into buf 0
    gload16(aptr0, al0[0]); gload16(aptr1, al1[0]);
    gload16(bptr0, bl0[0]); gload16(bptr1, bl1[0]);
    int cur = 0;
    for (int k0 = 0; k0 < D_DIM; k0 += BK) {
        __syncthreads();                       // drains buf[cur] loads (issued one iter ago)
        int nk = k0 + BK;
        if (nk < D_DIM) {
            int nb = cur ^ 1;
            gload16(aptr0 + nk, al0[nb]); gload16(aptr1 + nk, al1[nb]);
            gload16(bptr0 + nk, bl0[nb]); gload16(bptr1 + nk, bl1[nb]);
        }
        short8 af[4], bf[4];
#pragma unroll
        for (int i = 0; i < 4; ++i)
            af[i] = *(const short8*)&As[cur][(cr + wm + i * 16 + lm) * 8];
#pragma unroll
        for (int j = 0; j < 4; ++j)
            bf[j] = *(const short8*)&Bs[cur][(cr + wn + j * 16 + lm) * 8];
#pragma unroll
        for (int i = 0; i < 4; ++i)
#pragma unroll
            for (int j = 0; j < 4; ++j)
                acc[i][j] = __builtin_amdgcn_mfma_f32_16x16x32_bf16(af[i], bf[j], acc[i][j], 0, 0, 0);
        cur ^= 1;
    }
    int rbase = (lane >> 4) * 4;
    int cbase = lane & 15;
#pragma unroll
    for (int i = 0; i < 4; ++i) {
#pragma unroll
        for (int r = 0; r < 4; ++r) {
            int row = wm + i * 16 + rbase + r;
            if (row < m_count) {
                short* hp = hb + (size_t)(row0 + row) * F_DIM + n0 + wn + cbase;
#pragma unroll
                for (int j = 0; j < 4; ++j) {
                    float s = acc[i][j][r];
                    float g = 0.5f * s * (1.f + erff(s * 0.70710678118f));
                    hp[j * 16] = f2b(g);
                }
            }
        }
    }
}

// gemm2: split-K over F into 4 parts, fp32 partials into pbuf[kp][sorted_row][d]
__global__ __launch_bounds__(256) void gemm2_kernel(const short* __restrict__ hb,
                                                    const short* __restrict__ w2t,
                                                    const int* __restrict__ tmap,
                                                    float* __restrict__ pbuf) {
    __shared__ __align__(16) short As[2][4096];
    __shared__ __align__(16) short Bs[2][4096];
    int mt = blockIdx.y;
    int m_count = tmap[mt * 3 + 2];
    if (m_count == 0) return;
    int e = tmap[mt * 3 + 0];
    int row0 = tmap[mt * 3 + 1];
    int n0 = blockIdx.x * BN;
    int kp = blockIdx.z;
    int kbase = kp * (F_DIM / KSPLIT);
    int tid = threadIdx.x;
    int lane = tid & 63, wave = tid >> 6;
    int wm = (wave & 1) * 64, wn = (wave >> 1) * 64;
    int s0 = 2 * wave, s1 = s0 + 1;
    int c0s = s0 >> 1, m0s = (s0 & 1) * 64 + lane;
    int c1s = s1 >> 1, m1s = (s1 & 1) * 64 + lane;
    int am0 = m0s < m_count ? m0s : m_count - 1;
    int am1 = m1s < m_count ? m1s : m_count - 1;
    const short* aptr0 = hb + (size_t)(row0 + am0) * F_DIM + kbase + c0s * 8;
    const short* aptr1 = hb + (size_t)(row0 + am1) * F_DIM + kbase + c1s * 8;
    const short* wbase = w2t + (size_t)e * D_DIM * F_DIM;
    const short* bptr0 = wbase + (size_t)(n0 + m0s) * F_DIM + kbase + c0s * 8;
    const short* bptr1 = wbase + (size_t)(n0 + m1s) * F_DIM + kbase + c1s * 8;
    short* al0[2] = { &As[0][s0 * 512], &As[1][s0 * 512] };
    short* al1[2] = { &As[0][s1 * 512], &As[1][s1 * 512] };
    short* bl0[2] = { &Bs[0][s0 * 512], &Bs[1][s0 * 512] };
    short* bl1[2] = { &Bs[0][s1 * 512], &Bs[1][s1 * 512] };

    float4v acc[4][4];
#pragma unroll
    for (int i = 0; i < 4; ++i)
#pragma unroll
        for (int j = 0; j < 4; ++j) acc[i][j] = (float4v)(0.f);

    int cr = (lane >> 4) * 128;
    int lm = lane & 15;
    gload16(aptr0, al0[0]); gload16(aptr1, al1[0]);
    gload16(bptr0, bl0[0]); gload16(bptr1, bl1[0]);
    int cur = 0;
    const int KLEN = F_DIM / KSPLIT;
    for (int k0 = 0; k0 < KLEN; k0 += BK) {
        __syncthreads();
        int nk = k0 + BK;
        if (nk < KLEN) {
            int nb = cur ^ 1;
            gload16(aptr0 + nk, al0[nb]); gload16(aptr1 + nk, al1[nb]);
            gload16(bptr0 + nk, bl0[nb]); gload16(bptr1 + nk, bl1[nb]);
        }
        short8 af[4], bf[4];
#pragma unroll
        for (int i = 0; i < 4; ++i)
            af[i] = *(const short8*)&As[cur][(cr + wm + i * 16 + lm) * 8];
#pragma unroll
        for (int j = 0; j < 4; ++j)
            bf[j] = *(const short8*)&Bs[cur][(cr + wn + j * 16 + lm) * 8];
#pragma unroll
        for (int i = 0; i < 4; ++i)
#pragma unroll
            for (int j = 0; j < 4; ++j)
                acc[i][j] = __builtin_amdgcn_mfma_f32_16x16x32_bf16(af[i], bf[j], acc[i][j], 0, 0, 0);
        cur ^= 1;
    }
    float* pb = pbuf + (size_t)kp * T_TOK * D_DIM;
    int rbase = (lane >> 4) * 4;
    int cbase = lane & 15;
#pragma unroll
    for (int i = 0; i < 4; ++i) {
#pragma unroll
        for (int r = 0; r < 4; ++r) {
            int row = wm + i * 16 + rbase + r;
            if (row < m_count) {
                float* pp = pb + (size_t)(row0 + row) * D_DIM + n0 + wn + cbase;
#pragma unroll
                for (int j = 0; j < 4; ++j) pp[j * 16] = acc[i][j][r];
            }
        }
    }
}

// sum 4 split-K partials, scatter to original token row
__global__ __launch_bounds__(256) void reduce_kernel(const float* __restrict__ pbuf,
                                                     const int* __restrict__ sorted,
                                                     float* __restrict__ out) {
    int s = blockIdx.x;
    int d = threadIdx.x * 4;
    const float* p = pbuf + (size_t)s * D_DIM + d;
    float4v a = *(const float4v*)(p);
    a += *(const float4v*)(p + (size_t)1 * T_TOK * D_DIM);
    a += *(const float4v*)(p + (size_t)2 * T_TOK * D_DIM);
    a += *(const float4v*)(p + (size_t)3 * T_TOK * D_DIM);
    *(float4v*)(out + (size_t)sorted[s] * D_DIM + d) = a;
}

// ==================== FALLBACK PATH (small ws) ====================
__global__ __launch_bounds__(256) void gemm1_fb(const float* __restrict__ x,
                                                const float* __restrict__ w1,
                                                const int* __restrict__ sorted,
                                                const int* __restrict__ tmap,
                                                short* __restrict__ hbuf) {
    __shared__ short As[BM * LDK];
    __shared__ short Bs[BN * LDK];
    __shared__ int srow[BM];
    int mt = blockIdx.y;
    int m_count = tmap[mt * 3 + 2];
    if (m_count == 0) return;
    int e = tmap[mt * 3 + 0];
    int row0 = tmap[mt * 3 + 1];
    int n0 = blockIdx.x * BN;
    int tid = threadIdx.x;
    if (tid < BM) srow[tid] = sorted[row0 + (tid < m_count ? tid : m_count - 1)];
    __syncthreads();
    int lane = tid & 63, wave = tid >> 6;
    int wm = (wave & 1) * 64, wn = (wave >> 1) * 64;
    float4v acc[4][4];
#pragma unroll
    for (int i = 0; i < 4; ++i)
#pragma unroll
        for (int j = 0; j < 4; ++j) acc[i][j] = (float4v)(0.f);
    int ar = tid >> 1, ac = (tid & 1) * 16, bn = tid & 127, bq = (tid >> 7) * 16;
    const float* abase = x + (size_t)srow[ar] * D_DIM + ac;
    const float* bbase = w1 + (size_t)e * D_DIM * F_DIM + (size_t)bq * F_DIM + (n0 + bn);
    for (int k0 = 0; k0 < D_DIM; k0 += BK) {
        {
            const float* ap = abase + k0;
            float4v f0 = *(const float4v*)(ap);
            float4v f1 = *(const float4v*)(ap + 4);
            float4v f2 = *(const float4v*)(ap + 8);
            float4v f3 = *(const float4v*)(ap + 12);
            short8 t0, t1;
#pragma unroll
            for (int c = 0; c < 4; ++c) {
                t0[c] = f2b(f0[c]); t0[4 + c] = f2b(f1[c]);
                t1[c] = f2b(f2[c]); t1[4 + c] = f2b(f3[c]);
            }
            *(short8*)(&As[ar * LDK + ac]) = t0;
            *(short8*)(&As[ar * LDK + ac + 8]) = t1;
        }
        {
            const float* bp = bbase + (size_t)k0 * F_DIM;
            float v[16];
#pragma unroll
            for (int j = 0; j < 16; ++j) v[j] = bp[(size_t)j * F_DIM];
            short8 t0, t1;
#pragma unroll
            for (int j = 0; j < 8; ++j) { t0[j] = f2b(v[j]); t1[j] = f2b(v[8 + j]); }
            *(short8*)(&Bs[bn * LDK + bq]) = t0;
            *(short8*)(&Bs[bn * LDK + bq + 8]) = t1;
        }
        __syncthreads();
        short8 af[4], bf[4];
#pragma unroll
        for (int i = 0; i < 4; ++i)
            af[i] = *(const short8*)(&As[(wm + i * 16 + (lane & 15)) * LDK + (lane >> 4) * 8]);
#pragma unroll
        for (int j = 0; j < 4; ++j)
            bf[j] = *(const short8*)(&Bs[(wn + j * 16 + (lane & 15)) * LDK + (lane >> 4) * 8]);
#pragma unroll
        for (int i = 0; i < 4; ++i)
#pragma unroll
            for (int j = 0; j < 4; ++j)
                acc[i][j] = __builtin_amdgcn_mfma_f32_16x16x32_bf16(af[i], bf[j], acc[i][j], 0, 0, 0);
        __syncthreads();
    }
    int rbase = (lane >> 4) * 4, cbase = lane & 15;
#pragma unroll
    for (int i = 0; i < 4; ++i) {
#pragma unroll
        for (int r = 0; r < 4; ++r) {
            int row = wm + i * 16 + rbase + r;
            if (row < m_count) {
                short* hp = hbuf + (size_t)(row0 + row) * F_DIM + n0 + wn + cbase;
#pragma unroll
                for (int j = 0; j < 4; ++j) {
                    float s = acc[i][j][r];
                    float g = 0.5f * s * (1.f + erff(s * 0.70710678118f));
                    hp[j * 16] = f2b(g);
                }
            }
        }
    }
}

__global__ __launch_bounds__(256) void gemm2_fb(const short* __restrict__ hbuf,
                                                const float* __restrict__ w2,
                                                const int* __restrict__ sorted,
                                                const int* __restrict__ tmap,
                                                float* __restrict__ out) {
    __shared__ short As[BM * LDK];
    __shared__ short Bs[BN * LDK];
    __shared__ int srow[BM];
    int mt = blockIdx.y;
    int m_count = tmap[mt * 3 + 2];
    if (m_count == 0) return;
    int e = tmap[mt * 3 + 0];
    int row0 = tmap[mt * 3 + 1];
    int n0 = blockIdx.x * BN;
    int tid = threadIdx.x;
    if (tid < BM) srow[tid] = sorted[row0 + (tid < m_count ? tid : m_count - 1)];
    __syncthreads();
    int lane = tid & 63, wave = tid >> 6;
    int wm = (wave & 1) * 64, wn = (wave >> 1) * 64;
    float4v acc[4][4];
#pragma unroll
    for (int i = 0; i < 4; ++i)
#pragma unroll
        for (int j = 0; j < 4; ++j) acc[i][j] = (float4v)(0.f);
    int ar = tid >> 1, ac = (tid & 1) * 16, bn = tid & 127, bq = (tid >> 7) * 16;
    int arc = ar < m_count ? ar : m_count - 1;
    const short* abase = hbuf + (size_t)(row0 + arc) * F_DIM + ac;
    const float* bbase = w2 + (size_t)e * F_DIM * D_DIM + (size_t)bq * D_DIM + (n0 + bn);
    for (int k0 = 0; k0 < F_DIM; k0 += BK) {
        {
            const short* ap = abase + k0;
            *(short8*)(&As[ar * LDK + ac]) = *(const short8*)(ap);
            *(short8*)(&As[ar * LDK + ac + 8]) = *(const short8*)(ap + 8);
        }
        {
            const float* bp = bbase + (size_t)k0 * D_DIM;
            float v[16];
#pragma unroll
            for (int j = 0; j < 16; ++j) v[j] = bp[(size_t)j * D_DIM];
            short8 t0, t1;
#pragma unroll
            for (int j = 0; j < 8; ++j) { t0[j] = f2b(v[j]); t1[j] = f2b(v[8 + j]); }
            *(short8*)(&Bs[bn * LDK + bq]) = t0;
            *(short8*)(&Bs[bn * LDK + bq + 8]) = t1;
        }
        __syncthreads();
        short8 af[4], bf[4];
#pragma unroll
        for (int i = 0; i < 4; ++i)
            af[i] = *(const short8*)(&As[(wm + i * 16 + (lane & 15)) * LDK + (lane >> 4) * 8]);
#pragma unroll
        for (int j = 0; j < 4; ++j)
            bf[j] = *(const short8*)(&Bs[(wn + j * 16 + (lane & 15)) * LDK + (lane >> 4) * 8]);
#pragma unroll
        for (int i = 0; i < 4; ++i)
#pragma unroll
            for (int j = 0; j < 4; ++j)
                acc[i][j] = __builtin_amdgcn_mfma_f32_16x16x32_bf16(af[i], bf[j], acc[i][j], 0, 0, 0);
        __syncthreads();
    }
    int rbase = (lane >> 4) * 4, cbase = lane & 15;
#pragma unroll
    for (int i = 0; i < 4; ++i) {
#pragma unroll
        for (int r = 0; r < 4; ++r) {
            int row = wm + i * 16 + rbase + r;
            if (row < m_count) {
                float* op = out + (size_t)srow[row] * D_DIM + n0 + wn + cbase;
#pragma unroll
                for (int j = 0; j < 4; ++j) op[j * 16] = acc[i][j][r];
            }
        }
    }
}

extern "C" void kernel_launch(void* const* d_in, const int* in_sizes, int n_in,
                              void* d_out, int out_size, void* d_ws, size_t ws_size,
                              hipStream_t stream) {
    const float* x  = (const float*)d_in[0];
    const float* gw = (const float*)d_in[1];
    const float* w1 = (const float*)d_in[2];
    const float* w2 = (const float*)d_in[3];
    float* out = (float*)d_out;
    char* ws = (char*)d_ws;

    int* counts  = (int*)(ws);
    int* offsets = (int*)(ws + 64);
    int* tmap    = (int*)(ws + 128);
    int* eid     = (int*)(ws + 1024);
    int* rnk     = (int*)(ws + 17408);
    int* sorted  = (int*)(ws + 33792);

    const size_t XB_OFF  = 65536;
    const size_t W1T_OFF = XB_OFF  + (size_t)T_TOK * D_DIM * 2;
    const size_t W2T_OFF = W1T_OFF + (size_t)E_EXP * D_DIM * F_DIM * 2;
    const size_t HB_OFF  = W2T_OFF + (size_t)E_EXP * D_DIM * F_DIM * 2;
    const size_t PB_OFF  = HB_OFF  + (size_t)T_TOK * F_DIM * 2;
    const size_t NEED    = PB_OFF  + (size_t)KSPLIT * T_TOK * D_DIM * 4;

    hipMemsetAsync(counts, 0, 32, stream);
    router_kernel<<<T_TOK / 4, 256, 0, stream>>>(x, gw, eid, rnk, counts);
    prefix_kernel<<<1, 1, 0, stream>>>(counts, offsets, tmap);
    scatter_kernel<<<T_TOK / 256, 256, 0, stream>>>(eid, rnk, offsets, sorted);

    if (ws_size >= NEED) {
        short* xb   = (short*)(ws + XB_OFF);
        short* w1t  = (short*)(ws + W1T_OFF);
        short* w2t  = (short*)(ws + W2T_OFF);
        short* hb   = (short*)(ws + HB_OFF);
        float* pbuf = (float*)(ws + PB_OFF);
        xcvt_kernel<<<(T_TOK * D_DIM) / 1024, 256, 0, stream>>>(x, xb);
        transpose_cvt<<<dim3(F_DIM / 64, D_DIM / 64, E_EXP), 256, 0, stream>>>(w1, w1t, D_DIM, F_DIM);
        transpose_cvt<<<dim3(D_DIM / 64, F_DIM / 64, E_EXP), 256, 0, stream>>>(w2, w2t, F_DIM, D_DIM);
        gemm1_kernel<<<dim3(F_DIM / BN, MAX_TILES), 256, 0, stream>>>(xb, w1t, sorted, tmap, hb);
        gemm2_kernel<<<dim3(D_DIM / BN, MAX_TILES, KSPLIT), 256, 0, stream>>>(hb, w2t, tmap, pbuf);
        reduce_kernel<<<T_TOK, 256, 0, stream>>>(pbuf, sorted, out);
    } else {
        short* hbuf = (short*)(ws + 51200);
        gemm1_fb<<<dim3(F_DIM / BN, MAX_TILES), 256, 0, stream>>>(x, w1, sorted, tmap, hbuf);
        gemm2_fb<<<dim3(D_DIM / BN, MAX_TILES), 256, 0, stream>>>(hbuf, w2, sorted, tmap, out);
    }
}

// Round 4
// 587.422 us; speedup vs baseline: 1.0365x; 1.0365x over previous
//
#include <hip/hip_runtime.h>
#include <hip/hip_bf16.h>
#include <math.h>

#define T_TOK 4096
#define D_DIM 1024
#define E_EXP 8
#define F_DIM 4096
#define BM 128
#define BN 128
#define BK2 64
#define MAX_TILES 40    // sum_e ceil(cnt_e/128) <= 32 + 7 = 39
#define KSPLIT 4

typedef __attribute__((ext_vector_type(8))) short short8;
typedef __attribute__((ext_vector_type(4))) short short4v;
typedef __attribute__((ext_vector_type(4))) float float4v;

__device__ __forceinline__ short f2b(float f) {
    union { float f; unsigned u; } v; v.f = f;
    unsigned r = v.u + 0x7fffu + ((v.u >> 16) & 1u);   // RNE to bf16
    return (short)(r >> 16);
}

// async global->LDS, 16B per lane; global addr per-lane, LDS dest wave-uniform base
typedef const __attribute__((address_space(1))) unsigned gu32;
typedef __attribute__((address_space(3))) unsigned lu32;
__device__ __forceinline__ void gload16(const void* g, void* l) {
    __builtin_amdgcn_global_load_lds((gu32*)g, (lu32*)l, 16, 0, 0);
}

// inline tile map: block's (expert, row0, m_count) from counts[8]
__device__ __forceinline__ bool tile_lookup(const int* __restrict__ counts, int mt,
                                            int& e, int& row0, int& m_count) {
    int off = 0, acc = 0;
#pragma unroll
    for (int i = 0; i < E_EXP; ++i) {
        int c = counts[i];
        int nt = (c + BM - 1) >> 7;
        if (mt < acc + nt) {
            int j = mt - acc;
            e = i; row0 = off + j * BM;
            int mc = c - j * BM;
            m_count = mc > BM ? BM : mc;
            return true;
        }
        acc += nt; off += c;
    }
    return false;
}

// ---------------- router: fp32 logits + argmax + fused x->bf16 ----------------
__global__ void router_kernel(const float* __restrict__ x, const float* __restrict__ gw,
                              int* __restrict__ eid, int* __restrict__ rnk,
                              int* __restrict__ counts, short* __restrict__ xb) {
    int lane = threadIdx.x & 63;
    int wave = threadIdx.x >> 6;
    int t = blockIdx.x * 4 + wave;
    const float* xr = x + (size_t)t * D_DIM;
    short* xbr = xb + (size_t)t * D_DIM;
    float p[E_EXP];
#pragma unroll
    for (int e = 0; e < E_EXP; ++e) p[e] = 0.f;
#pragma unroll
    for (int i = 0; i < D_DIM / 64; ++i) {
        float v = xr[lane + 64 * i];
        xbr[lane + 64 * i] = f2b(v);
#pragma unroll
        for (int e = 0; e < E_EXP; ++e)
            p[e] = fmaf(v, gw[e * D_DIM + lane + 64 * i], p[e]);
    }
#pragma unroll
    for (int off = 32; off > 0; off >>= 1) {
#pragma unroll
        for (int e = 0; e < E_EXP; ++e) p[e] += __shfl_down(p[e], off, 64);
    }
    if (lane == 0) {
        int best = 0; float bv = p[0];
#pragma unroll
        for (int e = 1; e < E_EXP; ++e) if (p[e] > bv) { bv = p[e]; best = e; }
        eid[t] = best;
        rnk[t] = atomicAdd(&counts[best], 1);
    }
}

// ---------------- scatter with inline prefix ----------------
__global__ void scatter_kernel(const int* __restrict__ eid, const int* __restrict__ rnk,
                               const int* __restrict__ counts, int* __restrict__ sorted) {
    int t = blockIdx.x * 256 + threadIdx.x;
    int e = eid[t];
    int off = 0;
#pragma unroll
    for (int i = 0; i < E_EXP; ++i) off += (i < e) ? counts[i] : 0;
    sorted[off + rnk[t]] = t;
}

// ---------------- fp32 (E,R,C) -> bf16 (E,C,R) transpose+convert ----------------
// phase 1: LDS-transposed scalar writes (2-way banks = free); phase 2: b128 row reads
__global__ __launch_bounds__(256) void transpose_cvt(const float* __restrict__ src,
                                                     short* __restrict__ dst,
                                                     int R, int C) {
    __shared__ float t[64][65];
    size_t eoff = (size_t)blockIdx.z * R * C;
    const float* s = src + eoff;
    short* d = dst + eoff;
    int c0 = blockIdx.x * 64, r0 = blockIdx.y * 64;
    int tr = threadIdx.x >> 4;            // 0..15
    int tc = (threadIdx.x & 15) * 4;      // 0..60
#pragma unroll
    for (int p = 0; p < 4; ++p) {
        int r = tr + p * 16;
        float4v v = *(const float4v*)(s + (size_t)(r0 + r) * C + (c0 + tc));
        t[tc + 0][r] = v[0]; t[tc + 1][r] = v[1]; t[tc + 2][r] = v[2]; t[tc + 3][r] = v[3];
    }
    __syncthreads();
    int nl = threadIdx.x >> 2;            // column 0..63
    int kl = (threadIdx.x & 3) * 16;      // row segment 0/16/32/48
    short8 w0, w1;
#pragma unroll
    for (int q = 0; q < 8; ++q) { w0[q] = f2b(t[nl][kl + q]); w1[q] = f2b(t[nl][kl + 8 + q]); }
    short* dp = d + (size_t)(c0 + nl) * R + (r0 + kl);
    *(short8*)(dp) = w0;
    *(short8*)(dp + 8) = w1;
}

// ==================== GEMMs: BK=64 single-buffer ====================
// LDS per matrix: 16 KB = [h][c][m] chunks of 16 B; h=k-half (32), c=k-octet (8), m=row.
// Wave w stages octet c=w for all 128 rows, both halves: 4 gload16 per matrix per iter.
// Fragment read: chunk (h*512 + (lane>>4)*128 + row) -> quarter-wave reads 256 contiguous B.

__global__ __launch_bounds__(256) void gemm1_kernel(const short* __restrict__ xb,
                                                    const short* __restrict__ w1t,
                                                    const int* __restrict__ sorted,
                                                    const int* __restrict__ counts,
                                                    short* __restrict__ hb) {
    __shared__ __align__(16) short As[8192];
    __shared__ __align__(16) short Bs[8192];
    __shared__ int srow[BM];
    int e, row0, m_count;
    if (!tile_lookup(counts, blockIdx.y, e, row0, m_count)) return;
    int n0 = blockIdx.x * BN;
    int tid = threadIdx.x;
    if (tid < BM) srow[tid] = sorted[row0 + (tid < m_count ? tid : m_count - 1)];
    __syncthreads();

    int lane = tid & 63, wave = tid >> 6;
    int wm = (wave & 1) * 64, wn = (wave >> 1) * 64;
    const short* aA0 = xb + (size_t)srow[lane] * D_DIM + wave * 8;
    const short* aA1 = xb + (size_t)srow[64 + lane] * D_DIM + wave * 8;
    const short* wb = w1t + (size_t)e * F_DIM * D_DIM;
    const short* aB0 = wb + (size_t)(n0 + lane) * D_DIM + wave * 8;
    const short* aB1 = wb + (size_t)(n0 + 64 + lane) * D_DIM + wave * 8;
    short* lA00 = &As[(wave * 128) * 8];
    short* lA01 = &As[(wave * 128 + 64) * 8];
    short* lA10 = &As[4096 + (wave * 128) * 8];
    short* lA11 = &As[4096 + (wave * 128 + 64) * 8];
    short* lB00 = &Bs[(wave * 128) * 8];
    short* lB01 = &Bs[(wave * 128 + 64) * 8];
    short* lB10 = &Bs[4096 + (wave * 128) * 8];
    short* lB11 = &Bs[4096 + (wave * 128 + 64) * 8];

    float4v acc[4][4];
#pragma unroll
    for (int i = 0; i < 4; ++i)
#pragma unroll
        for (int j = 0; j < 4; ++j) acc[i][j] = (float4v)(0.f);

    int cr = (lane >> 4) * 128;
    int lm = lane & 15;
    for (int k0 = 0; k0 < D_DIM; k0 += BK2) {
        gload16(aA0 + k0, lA00);      gload16(aA1 + k0, lA01);
        gload16(aA0 + k0 + 32, lA10); gload16(aA1 + k0 + 32, lA11);
        gload16(aB0 + k0, lB00);      gload16(aB1 + k0, lB01);
        gload16(aB0 + k0 + 32, lB10); gload16(aB1 + k0 + 32, lB11);
        __syncthreads();
#pragma unroll
        for (int h = 0; h < 2; ++h) {
            short8 af[4], bf[4];
#pragma unroll
            for (int i = 0; i < 4; ++i)
                af[i] = *(const short8*)&As[h * 4096 + (cr + wm + i * 16 + lm) * 8];
#pragma unroll
            for (int j = 0; j < 4; ++j)
                bf[j] = *(const short8*)&Bs[h * 4096 + (cr + wn + j * 16 + lm) * 8];
#pragma unroll
            for (int i = 0; i < 4; ++i)
#pragma unroll
                for (int j = 0; j < 4; ++j)
                    acc[i][j] = __builtin_amdgcn_mfma_f32_16x16x32_bf16(af[i], bf[j], acc[i][j], 0, 0, 0);
        }
        __syncthreads();
    }
    int rbase = (lane >> 4) * 4;
    int cbase = lane & 15;
#pragma unroll
    for (int i = 0; i < 4; ++i) {
#pragma unroll
        for (int r = 0; r < 4; ++r) {
            int row = wm + i * 16 + rbase + r;
            if (row < m_count) {
                short* hp = hb + (size_t)(row0 + row) * F_DIM + n0 + wn + cbase;
#pragma unroll
                for (int j = 0; j < 4; ++j) {
                    float s = acc[i][j][r];
                    float g = 0.5f * s * (1.f + erff(s * 0.70710678118f));
                    hp[j * 16] = f2b(g);
                }
            }
        }
    }
}

// gemm2: split-K over F into 4 parts, fp32 partials into pbuf[kp][sorted_row][d]
__global__ __launch_bounds__(256) void gemm2_kernel(const short* __restrict__ hb,
                                                    const short* __restrict__ w2t,
                                                    const int* __restrict__ counts,
                                                    float* __restrict__ pbuf) {
    __shared__ __align__(16) short As[8192];
    __shared__ __align__(16) short Bs[8192];
    int e, row0, m_count;
    if (!tile_lookup(counts, blockIdx.y, e, row0, m_count)) return;
    int n0 = blockIdx.x * BN;
    int kp = blockIdx.z;
    int kbase = kp * (F_DIM / KSPLIT);
    int tid = threadIdx.x;
    int lane = tid & 63, wave = tid >> 6;
    int wm = (wave & 1) * 64, wn = (wave >> 1) * 64;
    int am0 = lane < m_count ? lane : m_count - 1;
    int am1 = (64 + lane) < m_count ? (64 + lane) : m_count - 1;
    const short* aA0 = hb + (size_t)(row0 + am0) * F_DIM + kbase + wave * 8;
    const short* aA1 = hb + (size_t)(row0 + am1) * F_DIM + kbase + wave * 8;
    const short* wb = w2t + (size_t)e * D_DIM * F_DIM;
    const short* aB0 = wb + (size_t)(n0 + lane) * F_DIM + kbase + wave * 8;
    const short* aB1 = wb + (size_t)(n0 + 64 + lane) * F_DIM + kbase + wave * 8;
    short* lA00 = &As[(wave * 128) * 8];
    short* lA01 = &As[(wave * 128 + 64) * 8];
    short* lA10 = &As[4096 + (wave * 128) * 8];
    short* lA11 = &As[4096 + (wave * 128 + 64) * 8];
    short* lB00 = &Bs[(wave * 128) * 8];
    short* lB01 = &Bs[(wave * 128 + 64) * 8];
    short* lB10 = &Bs[4096 + (wave * 128) * 8];
    short* lB11 = &Bs[4096 + (wave * 128 + 64) * 8];

    float4v acc[4][4];
#pragma unroll
    for (int i = 0; i < 4; ++i)
#pragma unroll
        for (int j = 0; j < 4; ++j) acc[i][j] = (float4v)(0.f);

    int cr = (lane >> 4) * 128;
    int lm = lane & 15;
    const int KLEN = F_DIM / KSPLIT;
    for (int k0 = 0; k0 < KLEN; k0 += BK2) {
        gload16(aA0 + k0, lA00);      gload16(aA1 + k0, lA01);
        gload16(aA0 + k0 + 32, lA10); gload16(aA1 + k0 + 32, lA11);
        gload16(aB0 + k0, lB00);      gload16(aB1 + k0, lB01);
        gload16(aB0 + k0 + 32, lB10); gload16(aB1 + k0 + 32, lB11);
        __syncthreads();
#pragma unroll
        for (int h = 0; h < 2; ++h) {
            short8 af[4], bf[4];
#pragma unroll
            for (int i = 0; i < 4; ++i)
                af[i] = *(const short8*)&As[h * 4096 + (cr + wm + i * 16 + lm) * 8];
#pragma unroll
            for (int j = 0; j < 4; ++j)
                bf[j] = *(const short8*)&Bs[h * 4096 + (cr + wn + j * 16 + lm) * 8];
#pragma unroll
            for (int i = 0; i < 4; ++i)
#pragma unroll
                for (int j = 0; j < 4; ++j)
                    acc[i][j] = __builtin_amdgcn_mfma_f32_16x16x32_bf16(af[i], bf[j], acc[i][j], 0, 0, 0);
        }
        __syncthreads();
    }
    float* pb = pbuf + (size_t)kp * T_TOK * D_DIM;
    int rbase = (lane >> 4) * 4;
    int cbase = lane & 15;
#pragma unroll
    for (int i = 0; i < 4; ++i) {
#pragma unroll
        for (int r = 0; r < 4; ++r) {
            int row = wm + i * 16 + rbase + r;
            if (row < m_count) {
                float* pp = pb + (size_t)(row0 + row) * D_DIM + n0 + wn + cbase;
#pragma unroll
                for (int j = 0; j < 4; ++j) pp[j * 16] = acc[i][j][r];
            }
        }
    }
}

// sum 4 split-K partials, scatter to original token row
__global__ __launch_bounds__(256) void reduce_kernel(const float* __restrict__ pbuf,
                                                     const int* __restrict__ sorted,
                                                     float* __restrict__ out) {
    int s = blockIdx.x;
    int d = threadIdx.x * 4;
    const float* p = pbuf + (size_t)s * D_DIM + d;
    float4v a = *(const float4v*)(p);
    a += *(const float4v*)(p + (size_t)1 * T_TOK * D_DIM);
    a += *(const float4v*)(p + (size_t)2 * T_TOK * D_DIM);
    a += *(const float4v*)(p + (size_t)3 * T_TOK * D_DIM);
    *(float4v*)(out + (size_t)sorted[s] * D_DIM + d) = a;
}

// ==================== FALLBACK PATH (small ws): fp32-staged GEMMs ====================
#define LDK 40
__global__ __launch_bounds__(256) void gemm1_fb(const float* __restrict__ x,
                                                const float* __restrict__ w1,
                                                const int* __restrict__ sorted,
                                                const int* __restrict__ counts,
                                                short* __restrict__ hbuf) {
    __shared__ short As[BM * LDK];
    __shared__ short Bs[BN * LDK];
    __shared__ int srow[BM];
    int e, row0, m_count;
    if (!tile_lookup(counts, blockIdx.y, e, row0, m_count)) return;
    int n0 = blockIdx.x * BN;
    int tid = threadIdx.x;
    if (tid < BM) srow[tid] = sorted[row0 + (tid < m_count ? tid : m_count - 1)];
    __syncthreads();
    int lane = tid & 63, wave = tid >> 6;
    int wm = (wave & 1) * 64, wn = (wave >> 1) * 64;
    float4v acc[4][4];
#pragma unroll
    for (int i = 0; i < 4; ++i)
#pragma unroll
        for (int j = 0; j < 4; ++j) acc[i][j] = (float4v)(0.f);
    int ar = tid >> 1, ac = (tid & 1) * 16, bn = tid & 127, bq = (tid >> 7) * 16;
    const float* abase = x + (size_t)srow[ar] * D_DIM + ac;
    const float* bbase = w1 + (size_t)e * D_DIM * F_DIM + (size_t)bq * F_DIM + (n0 + bn);
    for (int k0 = 0; k0 < D_DIM; k0 += 32) {
        {
            const float* ap = abase + k0;
            float4v f0 = *(const float4v*)(ap);
            float4v f1 = *(const float4v*)(ap + 4);
            float4v f2 = *(const float4v*)(ap + 8);
            float4v f3 = *(const float4v*)(ap + 12);
            short8 t0, t1;
#pragma unroll
            for (int c = 0; c < 4; ++c) {
                t0[c] = f2b(f0[c]); t0[4 + c] = f2b(f1[c]);
                t1[c] = f2b(f2[c]); t1[4 + c] = f2b(f3[c]);
            }
            *(short8*)(&As[ar * LDK + ac]) = t0;
            *(short8*)(&As[ar * LDK + ac + 8]) = t1;
        }
        {
            const float* bp = bbase + (size_t)k0 * F_DIM;
            float v[16];
#pragma unroll
            for (int j = 0; j < 16; ++j) v[j] = bp[(size_t)j * F_DIM];
            short8 t0, t1;
#pragma unroll
            for (int j = 0; j < 8; ++j) { t0[j] = f2b(v[j]); t1[j] = f2b(v[8 + j]); }
            *(short8*)(&Bs[bn * LDK + bq]) = t0;
            *(short8*)(&Bs[bn * LDK + bq + 8]) = t1;
        }
        __syncthreads();
        short8 af[4], bf[4];
#pragma unroll
        for (int i = 0; i < 4; ++i)
            af[i] = *(const short8*)(&As[(wm + i * 16 + (lane & 15)) * LDK + (lane >> 4) * 8]);
#pragma unroll
        for (int j = 0; j < 4; ++j)
            bf[j] = *(const short8*)(&Bs[(wn + j * 16 + (lane & 15)) * LDK + (lane >> 4) * 8]);
#pragma unroll
        for (int i = 0; i < 4; ++i)
#pragma unroll
            for (int j = 0; j < 4; ++j)
                acc[i][j] = __builtin_amdgcn_mfma_f32_16x16x32_bf16(af[i], bf[j], acc[i][j], 0, 0, 0);
        __syncthreads();
    }
    int rbase = (lane >> 4) * 4, cbase = lane & 15;
#pragma unroll
    for (int i = 0; i < 4; ++i) {
#pragma unroll
        for (int r = 0; r < 4; ++r) {
            int row = wm + i * 16 + rbase + r;
            if (row < m_count) {
                short* hp = hbuf + (size_t)(row0 + row) * F_DIM + n0 + wn + cbase;
#pragma unroll
                for (int j = 0; j < 4; ++j) {
                    float s = acc[i][j][r];
                    float g = 0.5f * s * (1.f + erff(s * 0.70710678118f));
                    hp[j * 16] = f2b(g);
                }
            }
        }
    }
}

__global__ __launch_bounds__(256) void gemm2_fb(const short* __restrict__ hbuf,
                                                const float* __restrict__ w2,
                                                const int* __restrict__ sorted,
                                                const int* __restrict__ counts,
                                                float* __restrict__ out) {
    __shared__ short As[BM * LDK];
    __shared__ short Bs[BN * LDK];
    __shared__ int srow[BM];
    int e, row0, m_count;
    if (!tile_lookup(counts, blockIdx.y, e, row0, m_count)) return;
    int n0 = blockIdx.x * BN;
    int tid = threadIdx.x;
    if (tid < BM) srow[tid] = sorted[row0 + (tid < m_count ? tid : m_count - 1)];
    __syncthreads();
    int lane = tid & 63, wave = tid >> 6;
    int wm = (wave & 1) * 64, wn = (wave >> 1) * 64;
    float4v acc[4][4];
#pragma unroll
    for (int i = 0; i < 4; ++i)
#pragma unroll
        for (int j = 0; j < 4; ++j) acc[i][j] = (float4v)(0.f);
    int ar = tid >> 1, ac = (tid & 1) * 16, bn = tid & 127, bq = (tid >> 7) * 16;
    int arc = ar < m_count ? ar : m_count - 1;
    const short* abase = hbuf + (size_t)(row0 + arc) * F_DIM + ac;
    const float* bbase = w2 + (size_t)e * F_DIM * D_DIM + (size_t)bq * D_DIM + (n0 + bn);
    for (int k0 = 0; k0 < F_DIM; k0 += 32) {
        {
            const short* ap = abase + k0;
            *(short8*)(&As[ar * LDK + ac]) = *(const short8*)(ap);
            *(short8*)(&As[ar * LDK + ac + 8]) = *(const short8*)(ap + 8);
        }
        {
            const float* bp = bbase + (size_t)k0 * D_DIM;
            float v[16];
#pragma unroll
            for (int j = 0; j < 16; ++j) v[j] = bp[(size_t)j * D_DIM];
            short8 t0, t1;
#pragma unroll
            for (int j = 0; j < 8; ++j) { t0[j] = f2b(v[j]); t1[j] = f2b(v[8 + j]); }
            *(short8*)(&Bs[bn * LDK + bq]) = t0;
            *(short8*)(&Bs[bn * LDK + bq + 8]) = t1;
        }
        __syncthreads();
        short8 af[4], bf[4];
#pragma unroll
        for (int i = 0; i < 4; ++i)
            af[i] = *(const short8*)(&As[(wm + i * 16 + (lane & 15)) * LDK + (lane >> 4) * 8]);
#pragma unroll
        for (int j = 0; j < 4; ++j)
            bf[j] = *(const short8*)(&Bs[(wn + j * 16 + (lane & 15)) * LDK + (lane >> 4) * 8]);
#pragma unroll
        for (int i = 0; i < 4; ++i)
#pragma unroll
            for (int j = 0; j < 4; ++j)
                acc[i][j] = __builtin_amdgcn_mfma_f32_16x16x32_bf16(af[i], bf[j], acc[i][j], 0, 0, 0);
        __syncthreads();
    }
    int rbase = (lane >> 4) * 4, cbase = lane & 15;
#pragma unroll
    for (int i = 0; i < 4; ++i) {
#pragma unroll
        for (int r = 0; r < 4; ++r) {
            int row = wm + i * 16 + rbase + r;
            if (row < m_count) {
                float* op = out + (size_t)srow[row] * D_DIM + n0 + wn + cbase;
#pragma unroll
                for (int j = 0; j < 4; ++j) op[j * 16] = acc[i][j][r];
            }
        }
    }
}

extern "C" void kernel_launch(void* const* d_in, const int* in_sizes, int n_in,
                              void* d_out, int out_size, void* d_ws, size_t ws_size,
                              hipStream_t stream) {
    const float* x  = (const float*)d_in[0];
    const float* gw = (const float*)d_in[1];
    const float* w1 = (const float*)d_in[2];
    const float* w2 = (const float*)d_in[3];
    float* out = (float*)d_out;
    char* ws = (char*)d_ws;

    int* counts = (int*)(ws);
    int* eid    = (int*)(ws + 1024);
    int* rnk    = (int*)(ws + 17408);
    int* sorted = (int*)(ws + 33792);

    const size_t XB_OFF  = 65536;
    const size_t W1T_OFF = XB_OFF  + (size_t)T_TOK * D_DIM * 2;
    const size_t W2T_OFF = W1T_OFF + (size_t)E_EXP * D_DIM * F_DIM * 2;
    const size_t HB_OFF  = W2T_OFF + (size_t)E_EXP * D_DIM * F_DIM * 2;
    const size_t PB_OFF  = HB_OFF  + (size_t)T_TOK * F_DIM * 2;
    const size_t NEED    = PB_OFF  + (size_t)KSPLIT * T_TOK * D_DIM * 4;

    short* xb = (short*)(ws + XB_OFF);

    hipMemsetAsync(counts, 0, 32, stream);
    router_kernel<<<T_TOK / 4, 256, 0, stream>>>(x, gw, eid, rnk, counts, xb);
    scatter_kernel<<<T_TOK / 256, 256, 0, stream>>>(eid, rnk, counts, sorted);

    if (ws_size >= NEED) {
        short* w1t  = (short*)(ws + W1T_OFF);
        short* w2t  = (short*)(ws + W2T_OFF);
        short* hb   = (short*)(ws + HB_OFF);
        float* pbuf = (float*)(ws + PB_OFF);
        transpose_cvt<<<dim3(F_DIM / 64, D_DIM / 64, E_EXP), 256, 0, stream>>>(w1, w1t, D_DIM, F_DIM);
        transpose_cvt<<<dim3(D_DIM / 64, F_DIM / 64, E_EXP), 256, 0, stream>>>(w2, w2t, F_DIM, D_DIM);
        gemm1_kernel<<<dim3(F_DIM / BN, MAX_TILES), 256, 0, stream>>>(xb, w1t, sorted, counts, hb);
        gemm2_kernel<<<dim3(D_DIM / BN, MAX_TILES, KSPLIT), 256, 0, stream>>>(hb, w2t, counts, pbuf);
        reduce_kernel<<<T_TOK, 256, 0, stream>>>(pbuf, sorted, out);
    } else {
        short* hbuf = (short*)(ws + 51200);
        gemm1_fb<<<dim3(F_DIM / BN, MAX_TILES), 256, 0, stream>>>(x, w1, sorted, counts, hbuf);
        gemm2_fb<<<dim3(D_DIM / BN, MAX_TILES), 256, 0, stream>>>(hbuf, w2, sorted, counts, out);
    }
}